// Round 1
// baseline (213.604 us; speedup 1.0000x reference)
//
#include <hip/hip_runtime.h>

// RankingLoss: loss = (1/N) * sum_i [ cnt_i>0 ? (sum_{j: t[j]<t[i]} max(0, margin - (p[i]-p[j]))) / cnt_i : 0 ]
// N=16384, margin=0.1, fp32 in/out.

constexpr float MARGIN = 0.1f;

__global__ __launch_bounds__(256) void rank_rows(const float* __restrict__ pred,
                                                 const float* __restrict__ target,
                                                 float* __restrict__ per_row,
                                                 int n) {
    const int i = blockIdx.x;
    const float ti = target[i];
    const float ci = MARGIN - pred[i];   // hinge = max(0, ci + pred[j])

    float sum = 0.f;
    int cnt = 0;
    for (int j = threadIdx.x; j < n; j += 256) {
        const float tj = target[j];
        const float pj = pred[j];
        if (tj < ti) {
            sum += fmaxf(0.f, ci + pj);
            cnt += 1;
        }
    }

    // wave (64-lane) shuffle reduction
    #pragma unroll
    for (int off = 32; off > 0; off >>= 1) {
        sum += __shfl_down(sum, off, 64);
        cnt += __shfl_down(cnt, off, 64);
    }

    __shared__ float s_sum[4];
    __shared__ int   s_cnt[4];
    const int lane = threadIdx.x & 63;
    const int wave = threadIdx.x >> 6;
    if (lane == 0) { s_sum[wave] = sum; s_cnt[wave] = cnt; }
    __syncthreads();
    if (threadIdx.x == 0) {
        const float s = s_sum[0] + s_sum[1] + s_sum[2] + s_sum[3];
        const int   c = s_cnt[0] + s_cnt[1] + s_cnt[2] + s_cnt[3];
        per_row[i] = (c > 0) ? (s / (float)c) : 0.f;
    }
}

__global__ __launch_bounds__(256) void final_reduce(const float* __restrict__ per_row,
                                                    float* __restrict__ out, int n) {
    double s = 0.0;
    for (int j = threadIdx.x; j < n; j += 256) s += (double)per_row[j];
    #pragma unroll
    for (int off = 32; off > 0; off >>= 1) s += __shfl_down(s, off, 64);

    __shared__ double sd[4];
    const int lane = threadIdx.x & 63;
    const int wave = threadIdx.x >> 6;
    if (lane == 0) sd[wave] = s;
    __syncthreads();
    if (threadIdx.x == 0) {
        out[0] = (float)((sd[0] + sd[1] + sd[2] + sd[3]) / (double)n);
    }
}

extern "C" void kernel_launch(void* const* d_in, const int* in_sizes, int n_in,
                              void* d_out, int out_size, void* d_ws, size_t ws_size,
                              hipStream_t stream) {
    const float* pred   = (const float*)d_in[0];
    const float* target = (const float*)d_in[1];
    const int n = in_sizes[0];                 // 16384

    float* per_row = (float*)d_ws;             // n floats of scratch (64 KiB)

    rank_rows<<<n, 256, 0, stream>>>(pred, target, per_row, n);
    final_reduce<<<1, 256, 0, stream>>>(per_row, (float*)d_out, n);
}

// Round 2
// 91.705 us; speedup vs baseline: 2.3293x; 2.3293x over previous
//
#include <hip/hip_runtime.h>

// RankingLoss: loss = (1/N) * sum_i [ cnt_i>0 ? (sum_{j: t[j]<t[i]} max(0, m - (p[i]-p[j]))) / cnt_i : 0 ]
// N=16384, margin=0.1, fp32 in/out.
//
// R rows per block: row constants in registers, each loaded (tj,pj) float4
// feeds R*4 pairs. cnt via __ballot+popc (scalar pipe, off the VALU).

constexpr float MARGIN = 0.1f;
constexpr int R = 8;      // rows per block
constexpr int T = 256;    // threads per block

__global__ __launch_bounds__(T) void rank_rows(const float* __restrict__ pred,
                                               const float* __restrict__ target,
                                               float* __restrict__ per_row,
                                               int n) {
    const int base = blockIdx.x * R;

    float ti[R], ci[R];
    #pragma unroll
    for (int r = 0; r < R; ++r) {
        ti[r] = target[base + r];
        ci[r] = MARGIN - pred[base + r];
    }

    float sum[R];
    unsigned int cnt[R];   // wave-uniform (ballot-counted)
    #pragma unroll
    for (int r = 0; r < R; ++r) { sum[r] = 0.f; cnt[r] = 0u; }

    const float4* __restrict__ t4 = (const float4*)target;
    const float4* __restrict__ p4 = (const float4*)pred;
    const int n4 = n >> 2;   // 4096, exact: no tail, all lanes always active

    for (int j = (int)threadIdx.x; j < n4; j += T) {
        const float4 tj = t4[j];
        const float4 pj = p4[j];
        #pragma unroll
        for (int r = 0; r < R; ++r) {
            const float tir = ti[r], cir = ci[r];
            {
                bool m = tj.x < tir;
                float h = fmaxf(0.f, cir + pj.x);
                sum[r] += m ? h : 0.f;
                cnt[r] += (unsigned)__popcll(__ballot(m));
            }
            {
                bool m = tj.y < tir;
                float h = fmaxf(0.f, cir + pj.y);
                sum[r] += m ? h : 0.f;
                cnt[r] += (unsigned)__popcll(__ballot(m));
            }
            {
                bool m = tj.z < tir;
                float h = fmaxf(0.f, cir + pj.z);
                sum[r] += m ? h : 0.f;
                cnt[r] += (unsigned)__popcll(__ballot(m));
            }
            {
                bool m = tj.w < tir;
                float h = fmaxf(0.f, cir + pj.w);
                sum[r] += m ? h : 0.f;
                cnt[r] += (unsigned)__popcll(__ballot(m));
            }
        }
    }

    // sum: shuffle-reduce across 64 lanes; cnt: already wave-uniform.
    __shared__ float        ls[T / 64][R];
    __shared__ unsigned int lc[T / 64][R];
    const int lane = threadIdx.x & 63;
    const int wv   = threadIdx.x >> 6;

    #pragma unroll
    for (int r = 0; r < R; ++r) {
        float s = sum[r];
        #pragma unroll
        for (int off = 32; off > 0; off >>= 1) s += __shfl_down(s, off, 64);
        if (lane == 0) { ls[wv][r] = s; lc[wv][r] = cnt[r]; }
    }
    __syncthreads();

    if ((int)threadIdx.x < R) {
        float s = 0.f;
        unsigned int c = 0u;
        #pragma unroll
        for (int w = 0; w < T / 64; ++w) { s += ls[w][threadIdx.x]; c += lc[w][threadIdx.x]; }
        per_row[base + threadIdx.x] = (c > 0u) ? (s / (float)c) : 0.f;
    }
}

__global__ __launch_bounds__(1024) void final_reduce(const float* __restrict__ per_row,
                                                     float* __restrict__ out, int n) {
    const float4* __restrict__ pr4 = (const float4*)per_row;
    const int n4 = n >> 2;
    double s = 0.0;
    for (int j = (int)threadIdx.x; j < n4; j += 1024) {
        float4 v = pr4[j];
        s += (double)v.x + (double)v.y + (double)v.z + (double)v.w;
    }
    #pragma unroll
    for (int off = 32; off > 0; off >>= 1) s += __shfl_down(s, off, 64);

    __shared__ double sd[16];
    const int lane = threadIdx.x & 63;
    const int wv   = threadIdx.x >> 6;
    if (lane == 0) sd[wv] = s;
    __syncthreads();
    if (threadIdx.x == 0) {
        double t = 0.0;
        #pragma unroll
        for (int w = 0; w < 16; ++w) t += sd[w];
        out[0] = (float)(t / (double)n);
    }
}

extern "C" void kernel_launch(void* const* d_in, const int* in_sizes, int n_in,
                              void* d_out, int out_size, void* d_ws, size_t ws_size,
                              hipStream_t stream) {
    const float* pred   = (const float*)d_in[0];
    const float* target = (const float*)d_in[1];
    const int n = in_sizes[0];                 // 16384

    float* per_row = (float*)d_ws;             // n floats of scratch (64 KiB)

    rank_rows<<<n / R, T, 0, stream>>>(pred, target, per_row, n);
    final_reduce<<<1, 1024, 0, stream>>>(per_row, (float*)d_out, n);
}